// Round 1
// baseline (270.106 us; speedup 1.0000x reference)
//
#include <hip/hip_runtime.h>
#include <stdint.h>
#include <stddef.h>

typedef _Float16 f16;
typedef _Float16 f16x8 __attribute__((ext_vector_type(8)));
typedef _Float16 f16x4 __attribute__((ext_vector_type(4)));
typedef float f32x4 __attribute__((ext_vector_type(4)));

// ---------------- async global->LDS (16B per lane, wave-uniform LDS base) ----
__device__ __forceinline__ void gload16(const void* g, void* l) {
    auto gp = (const __attribute__((address_space(1))) uint32_t*)(uintptr_t)g;
    auto lp = (__attribute__((address_space(3))) uint32_t*)(uintptr_t)l;
    __builtin_amdgcn_global_load_lds(gp, lp, 16, 0, 0);
}

// ---------------- prep: f32 -> f16 conversions --------------------------------
__global__ __launch_bounds__(256) void prep_k(const float* __restrict__ x,
                                              const float* __restrict__ wqkv,
                                              const float* __restrict__ wout,
                                              f16* __restrict__ xb,
                                              f16* __restrict__ wqb,
                                              f16* __restrict__ wob) {
    int tid = blockIdx.x * blockDim.x + threadIdx.x;
    int stride = gridDim.x * blockDim.x;
    for (int i = tid; i < 4194304; i += stride) {           // x: 16,777,216 f
        float4 v = ((const float4*)x)[i];
        f16x4 o = { (f16)v.x, (f16)v.y, (f16)v.z, (f16)v.w };
        *(f16x4*)(xb + (size_t)i * 4) = o;
    }
    for (int i = tid; i < 196608; i += stride) {            // w_qkv: 786,432 f
        float4 v = ((const float4*)wqkv)[i];
        f16x4 o = { (f16)v.x, (f16)v.y, (f16)v.z, (f16)v.w };
        *(f16x4*)(wqb + (size_t)i * 4) = o;
    }
    for (int i = tid; i < 65536; i += stride) {             // w_out: 262,144 f
        float4 v = ((const float4*)wout)[i];
        f16x4 o = { (f16)v.x, (f16)v.y, (f16)v.z, (f16)v.w };
        *(f16x4*)(wob + (size_t)i * 4) = o;
    }
}

// ---------------- generic 128x128 tile GEMM (K=512, BK=64), fp16 MFMA ---------
// MODE 0: qkv GEMM.  A=xb[32768][512], B=wqb[1536][512].
//         n-tile in Q/K range: row-permuted epilogue -> Q/K [bh][c][lh] (8B stores)
//         n-tile in V range:   swapped mfma -> V [bh][lh][d] (8B stores)
// MODE 1: S = Q K^T * 0.125 per bh (swap, fp32 out)
// MODE 2: Y = P V per bh (no swap, f16 out to y[b,l,c])
// MODE 3: out = y w_out^T + b_out (swap, f32 out)
template <int MODE>
__global__ __launch_bounds__(256) void gemm_k(const f16* __restrict__ A0,
                                              const f16* __restrict__ B0,
                                              void* __restrict__ C0,
                                              void* __restrict__ C1,
                                              void* __restrict__ C2,
                                              const float* __restrict__ bias) {
    __shared__ alignas(16) f16 ldsA[128 * 64];
    __shared__ alignas(16) f16 ldsB[128 * 64];

    const int lane = threadIdx.x & 63;
    const int wid = threadIdx.x >> 6;
    const int wr = wid >> 1, wc = wid & 1;

    const f16* At;
    const f16* Bt;
    int i3 = 0, tm, tn, bh = 0;
    if constexpr (MODE == 0) {
        tn = blockIdx.x * 128;
        tm = blockIdx.y * 128;
        i3 = tn >> 9;
        At = A0 + (size_t)tm * 512;
        Bt = B0 + (size_t)tn * 512;
    } else if constexpr (MODE == 1 || MODE == 2) {
        bh = blockIdx.y;
        tm = (blockIdx.x >> 2) * 128;
        tn = (blockIdx.x & 3) * 128;
        At = A0 + (size_t)bh * 262144 + (size_t)tm * 512;
        Bt = B0 + (size_t)bh * 262144 + (size_t)tn * 512;
    } else {
        tn = blockIdx.x * 128;
        tm = blockIdx.y * 128;
        At = A0 + (size_t)tm * 512;
        Bt = B0 + (size_t)tn * 512;
    }

    // staging source pointers (per lane); chunk i covers rows [ (wid*4+i)*8, +8 )
    const int srow = (wid * 4) * 8 + (lane >> 3);
    const int scol = (lane & 7) * 8;
    const f16* sa = At + (size_t)srow * 512 + scol;
    const f16* sb = Bt + (size_t)srow * 512 + scol;
    f16* da = ldsA + wid * 4 * 512;
    f16* db = ldsB + wid * 4 * 512;

    const bool permA = (MODE == 0 && i3 < 2);
    const bool swp = (MODE == 1) || (MODE == 3) || (MODE == 0 && i3 == 2);

    int aoff[4], boff[4];
#pragma unroll
    for (int i = 0; i < 4; ++i) {
        int rowi = permA ? ((lane & 15) * 8 + wr * 4 + i)
                         : (wr * 64 + i * 16 + (lane & 15));
        aoff[i] = rowi * 64 + (lane >> 4) * 8;
        boff[i] = (wc * 64 + i * 16 + (lane & 15)) * 64 + (lane >> 4) * 8;
    }

    f32x4 acc[4][4] = {};

    for (int kt = 0; kt < 8; ++kt) {
        __syncthreads();
#pragma unroll
        for (int i = 0; i < 4; ++i) gload16(sa + (size_t)i * 8 * 512 + kt * 64, da + i * 512);
#pragma unroll
        for (int i = 0; i < 4; ++i) gload16(sb + (size_t)i * 8 * 512 + kt * 64, db + i * 512);
        __syncthreads();
#pragma unroll
        for (int kk = 0; kk < 2; ++kk) {
            f16x8 af[4], bv[4];
#pragma unroll
            for (int i = 0; i < 4; ++i) af[i] = *(const f16x8*)&ldsA[aoff[i] + kk * 32];
#pragma unroll
            for (int j = 0; j < 4; ++j) bv[j] = *(const f16x8*)&ldsB[boff[j] + kk * 32];
            if (swp) {
#pragma unroll
                for (int i = 0; i < 4; ++i)
#pragma unroll
                    for (int j = 0; j < 4; ++j)
                        acc[i][j] = __builtin_amdgcn_mfma_f32_16x16x32_f16(bv[j], af[i], acc[i][j], 0, 0, 0);
            } else {
#pragma unroll
                for (int i = 0; i < 4; ++i)
#pragma unroll
                    for (int j = 0; j < 4; ++j)
                        acc[i][j] = __builtin_amdgcn_mfma_f32_16x16x32_f16(af[i], bv[j], acc[i][j], 0, 0, 0);
            }
        }
    }

    // ---------------- epilogues ----------------
    if constexpr (MODE == 0) {
        int b = tm >> 12;
        if (i3 < 2) {
            // C row r -> global m = tm + perm(r), perm(r)=(r&15)*8+(r>>4)
            // per lane: 4 regs = 4 consecutive lh, h = wr*4+i
            f16* dst = (f16*)(i3 == 0 ? C0 : C1);
            int lh0 = ((tm & 4095) >> 3) + (lane >> 4) * 4;
            int ic0 = (tn & 511) + wc * 64 + (lane & 15);
#pragma unroll
            for (int i = 0; i < 4; ++i) {
                int h = wr * 4 + i;
#pragma unroll
                for (int j = 0; j < 4; ++j) {
                    int ic = ic0 + j * 16;
                    f16x4 pk = { (f16)acc[i][j][0], (f16)acc[i][j][1],
                                 (f16)acc[i][j][2], (f16)acc[i][j][3] };
                    *(f16x4*)(dst + ((size_t)((b * 8 + h) * 512 + ic)) * 512 + lh0) = pk;
                }
            }
        } else {
            // swapped: per lane 4 regs = 4 consecutive d at fixed m
            f16* dst = (f16*)C2;
#pragma unroll
            for (int i = 0; i < 4; ++i) {
                int mloc = wr * 64 + i * 16 + (lane & 15);
                int h = mloc & 7;
                int lh = ((tm & 4095) + mloc) >> 3;
#pragma unroll
                for (int j = 0; j < 4; ++j) {
                    int d0 = (tn - 1024) + wc * 64 + j * 16 + (lane >> 4) * 4;
                    f16x4 pk = { (f16)acc[i][j][0], (f16)acc[i][j][1],
                                 (f16)acc[i][j][2], (f16)acc[i][j][3] };
                    *(f16x4*)(dst + ((size_t)((b * 8 + h) * 512 + lh)) * 512 + d0) = pk;
                }
            }
        }
    } else if constexpr (MODE == 1) {
        float* S = (float*)C0 + (size_t)bh * 262144;
#pragma unroll
        for (int i = 0; i < 4; ++i) {
            int cm = tm + wr * 64 + i * 16 + (lane & 15);
#pragma unroll
            for (int j = 0; j < 4; ++j) {
                int d0 = tn + wc * 64 + j * 16 + (lane >> 4) * 4;
                f32x4 v = acc[i][j] * 0.125f;
                *(f32x4*)(S + (size_t)cm * 512 + d0) = v;
            }
        }
    } else if constexpr (MODE == 2) {
        f16* yb = (f16*)C0;
        int b = bh >> 3, h = bh & 7;
#pragma unroll
        for (int i = 0; i < 4; ++i) {
            int c0 = tm + wr * 64 + i * 16 + (lane >> 4) * 4;
#pragma unroll
            for (int j = 0; j < 4; ++j) {
                int l = tn + wc * 64 + j * 16 + (lane & 15);
                size_t gl = (size_t)b * 4096 + (size_t)l * 8 + h;
                f16x4 pk = { (f16)acc[i][j][0], (f16)acc[i][j][1],
                             (f16)acc[i][j][2], (f16)acc[i][j][3] };
                *(f16x4*)(yb + gl * 512 + c0) = pk;
            }
        }
    } else {
        float* O = (float*)C0;
#pragma unroll
        for (int i = 0; i < 4; ++i) {
            int m = tm + wr * 64 + i * 16 + (lane & 15);
#pragma unroll
            for (int j = 0; j < 4; ++j) {
                int n0 = tn + wc * 64 + j * 16 + (lane >> 4) * 4;
                float4 bvv = *(const float4*)(bias + n0);
                f32x4 v = acc[i][j];
                v[0] += bvv.x; v[1] += bvv.y; v[2] += bvv.z; v[3] += bvv.w;
                *(f32x4*)(O + (size_t)m * 512 + n0) = v;
            }
        }
    }
}

// ---------------- softmax over 512-wide rows (wave per row) -------------------
__global__ __launch_bounds__(256) void softmax_k(const float* __restrict__ S,
                                                 f16* __restrict__ P) {
    int row = blockIdx.x * 4 + (threadIdx.x >> 6);
    int lane = threadIdx.x & 63;
    const float* src = S + (size_t)row * 512 + lane * 8;
    float v[8];
    *(float4*)&v[0] = *(const float4*)src;
    *(float4*)&v[4] = *(const float4*)(src + 4);
    float m = v[0];
#pragma unroll
    for (int i = 1; i < 8; ++i) m = fmaxf(m, v[i]);
#pragma unroll
    for (int off = 1; off < 64; off <<= 1) m = fmaxf(m, __shfl_xor(m, off, 64));
    float s = 0.f, e[8];
#pragma unroll
    for (int i = 0; i < 8; ++i) { e[i] = __expf(v[i] - m); s += e[i]; }
#pragma unroll
    for (int off = 1; off < 64; off <<= 1) s += __shfl_xor(s, off, 64);
    float inv = 1.0f / s;
    f16x8 pk;
#pragma unroll
    for (int i = 0; i < 8; ++i) pk[i] = (f16)(e[i] * inv);
    *(f16x8*)(P + (size_t)row * 512 + lane * 8) = pk;
}

// ---------------- launch ------------------------------------------------------
extern "C" void kernel_launch(void* const* d_in, const int* in_sizes, int n_in,
                              void* d_out, int out_size, void* d_ws, size_t ws_size,
                              hipStream_t stream) {
    const float* x = (const float*)d_in[0];
    const float* wqkv = (const float*)d_in[1];
    const float* wout = (const float*)d_in[2];
    const float* bout = (const float*)d_in[3];
    float* out = (float*)d_out;
    char* ws = (char*)d_ws;
    const size_t MBs = 1u << 20;

    f16* xb  = (f16*)(ws + 0);            // 32MB
    f16* wqb = (f16*)(ws + 32 * MBs);     // 1.5MB
    f16* wob = (f16*)(ws + 34 * MBs);     // 0.5MB
    f16* Qb  = (f16*)(ws + 35 * MBs);     // 32MB
    f16* Kb  = (f16*)(ws + 67 * MBs);     // 32MB
    f16* Vb  = (f16*)(ws + 99 * MBs);     // 32MB
    float* Sb = (float*)(ws + 131 * MBs); // 64MB  (total 195MB)
    f16* Pb  = xb;                        // alias: xb dead after qkv GEMM
    f16* yb  = Qb;                        // alias: Q dead after S GEMM

    prep_k<<<1024, 256, 0, stream>>>(x, wqkv, wout, xb, wqb, wob);
    gemm_k<0><<<dim3(12, 256), 256, 0, stream>>>(xb, wqb, Qb, Kb, Vb, nullptr);
    gemm_k<1><<<dim3(16, 64), 256, 0, stream>>>(Qb, Kb, Sb, nullptr, nullptr, nullptr);
    softmax_k<<<8192, 256, 0, stream>>>(Sb, Pb);
    gemm_k<2><<<dim3(16, 64), 256, 0, stream>>>(Pb, Vb, yb, nullptr, nullptr, nullptr);
    gemm_k<3><<<dim3(4, 256), 256, 0, stream>>>(yb, wob, out, nullptr, nullptr, bout);
}

// Round 2
// 208.310 us; speedup vs baseline: 1.2967x; 1.2967x over previous
//
#include <hip/hip_runtime.h>
#include <stdint.h>
#include <stddef.h>

typedef _Float16 f16;
typedef _Float16 f16x8 __attribute__((ext_vector_type(8)));
typedef _Float16 f16x4 __attribute__((ext_vector_type(4)));
typedef float f32x4 __attribute__((ext_vector_type(4)));

__device__ __forceinline__ void gload16(const void* g, void* l) {
    auto gp = (const __attribute__((address_space(1))) uint32_t*)(uintptr_t)g;
    auto lp = (__attribute__((address_space(3))) uint32_t*)(uintptr_t)l;
    __builtin_amdgcn_global_load_lds(gp, lp, 16, 0, 0);
}

__device__ __forceinline__ f16x4 cvt4(f32x4 v) {
    return f16x4{ (f16)v[0], (f16)v[1], (f16)v[2], (f16)v[3] };
}

// ---------------- prep: f32 -> f16 conversions --------------------------------
__global__ __launch_bounds__(256) void prep_k(const float* __restrict__ x,
                                              const float* __restrict__ wqkv,
                                              const float* __restrict__ wout,
                                              f16* __restrict__ xb,
                                              f16* __restrict__ wqb,
                                              f16* __restrict__ wob) {
    int tid = blockIdx.x * blockDim.x + threadIdx.x;
    int stride = gridDim.x * blockDim.x;
    for (int i = tid; i < 4194304; i += stride) {
        float4 v = ((const float4*)x)[i];
        *(f16x4*)(xb + (size_t)i * 4) = f16x4{ (f16)v.x, (f16)v.y, (f16)v.z, (f16)v.w };
    }
    for (int i = tid; i < 196608; i += stride) {
        float4 v = ((const float4*)wqkv)[i];
        *(f16x4*)(wqb + (size_t)i * 4) = f16x4{ (f16)v.x, (f16)v.y, (f16)v.z, (f16)v.w };
    }
    for (int i = tid; i < 65536; i += stride) {
        float4 v = ((const float4*)wout)[i];
        *(f16x4*)(wob + (size_t)i * 4) = f16x4{ (f16)v.x, (f16)v.y, (f16)v.z, (f16)v.w };
    }
}

// ---------------- 256x256 tile, BK=64, 8-wave phase-interleaved GEMM ----------
// All ops: C[m][n] = sum_k A[m][k]*B[n][k], K=512 (8 K-tiles), row stride 512.
// MODE 0: qkv (M=32768, N=1536). Q/K n-tiles: permuted A reads -> [bh][c][lh].
//         V n-tiles: swapped -> [bh][lh][d].
// MODE 1: S = Q K^T * 0.125 per bh (swapped, f32 out)
// MODE 2: Y = P V per bh (normal, f16 out to y[token][c])
// MODE 3: out = y w_out^T + b_out (swapped, f32 out)

#define MFMA_BLK(MH, NH, AF, BF) do {                                           \
    __builtin_amdgcn_s_setprio(1);                                              \
    if (swp) {                                                                  \
        for (int mi = 0; mi < 4; ++mi)                                          \
            for (int ni = 0; ni < 2; ++ni)                                      \
                for (int kk = 0; kk < 2; ++kk)                                  \
                    acc[(MH)*4+mi][(NH)*2+ni] = __builtin_amdgcn_mfma_f32_16x16x32_f16( \
                        BF[ni][kk], AF[mi][kk], acc[(MH)*4+mi][(NH)*2+ni], 0, 0, 0);    \
    } else {                                                                    \
        for (int mi = 0; mi < 4; ++mi)                                          \
            for (int ni = 0; ni < 2; ++ni)                                      \
                for (int kk = 0; kk < 2; ++kk)                                  \
                    acc[(MH)*4+mi][(NH)*2+ni] = __builtin_amdgcn_mfma_f32_16x16x32_f16( \
                        AF[mi][kk], BF[ni][kk], acc[(MH)*4+mi][(NH)*2+ni], 0, 0, 0);    \
    }                                                                           \
    __builtin_amdgcn_s_setprio(0);                                              \
} while (0)

#define STAGE_A(h, li) gload16(srcA[(h)*2+(li)], &lds[nb][0][((h)*128+(li)*64+wid*8)*64])
#define STAGE_B(h, li) gload16(srcB[(h)*2+(li)], &lds[nb][1][((h)*128+(li)*64+wid*8)*64])

template <int MODE>
__global__ __launch_bounds__(512, 2) void g8_k(const f16* __restrict__ A0,
                                               const f16* __restrict__ B0,
                                               void* __restrict__ C0,
                                               void* __restrict__ C1,
                                               void* __restrict__ C2,
                                               const float* __restrict__ bias) {
    __shared__ f16 lds[2][2][16384];   // [buf][A/B][256 rows x 64 k], 128 KiB

    const int tid = threadIdx.x;
    const int lane = tid & 63;
    const int wid = tid >> 6;
    const int wr = wid >> 2;   // 0..1
    const int wc = wid & 3;    // 0..3

    int tm, tn, bh = 0;
    bool qk = false, swp;
    const int bid = blockIdx.x;
    if constexpr (MODE == 0) {
        int swz = (bid & 7) * 96 + (bid >> 3);          // 768 blocks, bijective
        tm = (swz / 6) * 256; tn = (swz % 6) * 256;
        qk = tn < 1024; swp = !qk;
    } else if constexpr (MODE == 1 || MODE == 2) {
        int swz = (bid & 7) * 32 + (bid >> 3);          // 256 blocks
        bh = swz >> 2; tm = ((swz >> 1) & 1) * 256; tn = (swz & 1) * 256;
        swp = (MODE == 1);
    } else {
        int swz = (bid & 7) * 32 + (bid >> 3);          // 256 blocks
        tm = (swz >> 1) * 256; tn = (swz & 1) * 256;
        swp = true;
    }

    const size_t bhoff = (MODE == 1 || MODE == 2) ? (size_t)bh * 262144 : 0;
    const f16* At = A0 + bhoff + (size_t)tm * 512;
    const f16* Bt = B0 + bhoff + (size_t)tn * 512;

    // staging source pointers, pre-swizzled: chunk c8 = (tid&7) ^ s(r),
    // s(r) = (r&7)^((r>>3)&7).  LDS dest stays linear (lane*16B).
    const f16* srcA[4];
    const f16* srcB[4];
#pragma unroll
    for (int h = 0; h < 2; ++h)
#pragma unroll
        for (int li = 0; li < 2; ++li) {
            int r = h * 128 + li * 64 + (tid >> 3);
            int c8 = (tid & 7) ^ ((r & 7) ^ ((r >> 3) & 7));
            srcA[h * 2 + li] = At + (size_t)r * 512 + c8 * 8;
            srcB[h * 2 + li] = Bt + (size_t)r * 512 + c8 * 8;
        }

    // fragment LDS offsets (f16 units), swizzled reads
    int aoff[16];  // [mh][mi][kk]
    int boff[8];   // [nh][ni][kk]
#pragma unroll
    for (int mh = 0; mh < 2; ++mh)
#pragma unroll
        for (int mi = 0; mi < 4; ++mi) {
            int r = qk ? (mh * 128 + (lane & 15) * 8 + wr * 4 + mi)
                       : (mh * 128 + wr * 64 + mi * 16 + (lane & 15));
#pragma unroll
            for (int kk = 0; kk < 2; ++kk) {
                int c8 = (lane >> 4) + kk * 4;
                aoff[mh * 8 + mi * 2 + kk] = r * 64 + (c8 ^ ((r & 7) ^ ((r >> 3) & 7))) * 8;
            }
        }
#pragma unroll
    for (int nh = 0; nh < 2; ++nh)
#pragma unroll
        for (int ni = 0; ni < 2; ++ni) {
            int r = nh * 128 + wc * 32 + ni * 16 + (lane & 15);
#pragma unroll
            for (int kk = 0; kk < 2; ++kk) {
                int c8 = (lane >> 4) + kk * 4;
                boff[nh * 4 + ni * 2 + kk] = r * 64 + (c8 ^ ((r & 7) ^ ((r >> 3) & 7))) * 8;
            }
        }

    f32x4 acc[8][4] = {};
    f16x8 afA[4][2], afB[4][2], bf0[2][2], bf1[2][2];

    // ---- prologue: stage tile 0 (order A0 B0 B1 A1), wait A0+B0
    {
        int nb = 0;
        STAGE_A(0, 0); STAGE_A(0, 1);
        STAGE_B(0, 0); STAGE_B(0, 1);
        STAGE_B(1, 0); STAGE_B(1, 1);
        STAGE_A(1, 0); STAGE_A(1, 1);
#pragma unroll
        for (int i = 0; i < 4; ++i) { srcA[i] += 64; srcB[i] += 64; }
    }
    asm volatile("s_waitcnt vmcnt(4)" ::: "memory");
    __builtin_amdgcn_s_barrier();

#pragma unroll 1
    for (int t = 0; t < 7; ++t) {
        const f16* LA = &lds[t & 1][0][0];
        const f16* LB = &lds[t & 1][1][0];
        const int nb = (t + 1) & 1;

        // ---- P0 (mh0,nh0): read afA+bf0, stage A0,B0 of t+1, vmcnt(6)
#pragma unroll
        for (int mi = 0; mi < 4; ++mi)
#pragma unroll
            for (int kk = 0; kk < 2; ++kk)
                afA[mi][kk] = *(const f16x8*)(LA + aoff[mi * 2 + kk]);
#pragma unroll
        for (int ni = 0; ni < 2; ++ni)
#pragma unroll
            for (int kk = 0; kk < 2; ++kk)
                bf0[ni][kk] = *(const f16x8*)(LB + boff[ni * 2 + kk]);
        STAGE_A(0, 0); STAGE_A(0, 1); STAGE_B(0, 0); STAGE_B(0, 1);
        asm volatile("s_waitcnt vmcnt(6)" ::: "memory");
        __builtin_amdgcn_s_barrier();
        MFMA_BLK(0, 0, afA, bf0);
        __builtin_amdgcn_s_barrier();

        // ---- P1 (mh0,nh1): read bf1, stage B1, vmcnt(6)
#pragma unroll
        for (int ni = 0; ni < 2; ++ni)
#pragma unroll
            for (int kk = 0; kk < 2; ++kk)
                bf1[ni][kk] = *(const f16x8*)(LB + boff[4 + ni * 2 + kk]);
        STAGE_B(1, 0); STAGE_B(1, 1);
        asm volatile("s_waitcnt vmcnt(6)" ::: "memory");
        __builtin_amdgcn_s_barrier();
        MFMA_BLK(0, 1, afA, bf1);
        __builtin_amdgcn_s_barrier();

        // ---- P2 (mh1,nh1): read afB, stage A1, no wait
#pragma unroll
        for (int mi = 0; mi < 4; ++mi)
#pragma unroll
            for (int kk = 0; kk < 2; ++kk)
                afB[mi][kk] = *(const f16x8*)(LA + aoff[8 + mi * 2 + kk]);
        STAGE_A(1, 0); STAGE_A(1, 1);
        __builtin_amdgcn_s_barrier();
        MFMA_BLK(1, 1, afB, bf1);
        __builtin_amdgcn_s_barrier();

        // ---- P3 (mh1,nh0): no reads/stage, vmcnt(4) covers next P0 reads
        asm volatile("s_waitcnt vmcnt(4)" ::: "memory");
        __builtin_amdgcn_s_barrier();
        MFMA_BLK(1, 0, afB, bf0);
        __builtin_amdgcn_s_barrier();

#pragma unroll
        for (int i = 0; i < 4; ++i) { srcA[i] += 64; srcB[i] += 64; }
    }

    // ---- final tile t=7 (buf 1), drain 2 -> 0
    {
        const f16* LA = &lds[1][0][0];
        const f16* LB = &lds[1][1][0];
#pragma unroll
        for (int mi = 0; mi < 4; ++mi)
#pragma unroll
            for (int kk = 0; kk < 2; ++kk)
                afA[mi][kk] = *(const f16x8*)(LA + aoff[mi * 2 + kk]);
#pragma unroll
        for (int ni = 0; ni < 2; ++ni)
#pragma unroll
            for (int kk = 0; kk < 2; ++kk)
                bf0[ni][kk] = *(const f16x8*)(LB + boff[ni * 2 + kk]);
        asm volatile("s_waitcnt vmcnt(2)" ::: "memory");
        __builtin_amdgcn_s_barrier();
        MFMA_BLK(0, 0, afA, bf0);
        __builtin_amdgcn_s_barrier();

#pragma unroll
        for (int ni = 0; ni < 2; ++ni)
#pragma unroll
            for (int kk = 0; kk < 2; ++kk)
                bf1[ni][kk] = *(const f16x8*)(LB + boff[4 + ni * 2 + kk]);
        asm volatile("s_waitcnt vmcnt(0)" ::: "memory");
        __builtin_amdgcn_s_barrier();
        MFMA_BLK(0, 1, afA, bf1);
        __builtin_amdgcn_s_barrier();

#pragma unroll
        for (int mi = 0; mi < 4; ++mi)
#pragma unroll
            for (int kk = 0; kk < 2; ++kk)
                afB[mi][kk] = *(const f16x8*)(LA + aoff[8 + mi * 2 + kk]);
        __builtin_amdgcn_s_barrier();
        MFMA_BLK(1, 1, afB, bf1);
        MFMA_BLK(1, 0, afB, bf0);
    }

    // ---------------- epilogues ----------------
    if constexpr (MODE == 0) {
        const int b = tm >> 12;
        if (qk) {
            f16* dst = (f16*)(tn < 512 ? C0 : C1);
            const int lt = (tm & 4095) >> 3;
            const int cb = (tn & 511) + wc * 32;
#pragma unroll
            for (int mf = 0; mf < 8; ++mf) {
                int h = wr * 4 + (mf & 3);
                int lh0 = lt + (mf >> 2) * 16 + (lane >> 4) * 4;
#pragma unroll
                for (int nf = 0; nf < 4; ++nf) {
                    int c = cb + (nf >> 1) * 128 + (nf & 1) * 16 + (lane & 15);
                    *(f16x4*)(dst + ((size_t)((b * 8 + h) * 512 + c)) * 512 + lh0) =
                        cvt4(acc[mf][nf]);
                }
            }
        } else {
            f16* dst = (f16*)C2;
#pragma unroll
            for (int mf = 0; mf < 8; ++mf) {
                int m = (tm & 4095) + (mf >> 2) * 128 + wr * 64 + (mf & 3) * 16 + (lane & 15);
                int h = m & 7;
                int lh = m >> 3;
#pragma unroll
                for (int nf = 0; nf < 4; ++nf) {
                    int d0 = (tn - 1024) + (nf >> 1) * 128 + wc * 32 + (nf & 1) * 16 + (lane >> 4) * 4;
                    *(f16x4*)(dst + ((size_t)((b * 8 + h) * 512 + lh)) * 512 + d0) =
                        cvt4(acc[mf][nf]);
                }
            }
        }
    } else if constexpr (MODE == 1) {
        float* S = (float*)C0 + (size_t)bh * 262144;
#pragma unroll
        for (int mf = 0; mf < 8; ++mf) {
            int cm = tm + (mf >> 2) * 128 + wr * 64 + (mf & 3) * 16 + (lane & 15);
#pragma unroll
            for (int nf = 0; nf < 4; ++nf) {
                int d0 = tn + (nf >> 1) * 128 + wc * 32 + (nf & 1) * 16 + (lane >> 4) * 4;
                *(f32x4*)(S + (size_t)cm * 512 + d0) = acc[mf][nf] * 0.125f;
            }
        }
    } else if constexpr (MODE == 2) {
        f16* yb = (f16*)C0;
        const int b = bh >> 3, h = bh & 7;
#pragma unroll
        for (int mf = 0; mf < 8; ++mf) {
            int c0 = tm + (mf >> 2) * 128 + wr * 64 + (mf & 3) * 16 + (lane >> 4) * 4;
#pragma unroll
            for (int nf = 0; nf < 4; ++nf) {
                int l = tn + (nf >> 1) * 128 + wc * 32 + (nf & 1) * 16 + (lane & 15);
                size_t tok = (size_t)b * 4096 + (size_t)l * 8 + h;
                *(f16x4*)(yb + tok * 512 + c0) = cvt4(acc[mf][nf]);
            }
        }
    } else {
        float* O = (float*)C0;
#pragma unroll
        for (int mf = 0; mf < 8; ++mf) {
            int m = tm + (mf >> 2) * 128 + wr * 64 + (mf & 3) * 16 + (lane & 15);
#pragma unroll
            for (int nf = 0; nf < 4; ++nf) {
                int n0 = tn + (nf >> 1) * 128 + wc * 32 + (nf & 1) * 16 + (lane >> 4) * 4;
                float4 bv = *(const float4*)(bias + n0);
                f32x4 v = acc[mf][nf];
                v[0] += bv.x; v[1] += bv.y; v[2] += bv.z; v[3] += bv.w;
                *(f32x4*)(O + (size_t)m * 512 + n0) = v;
            }
        }
    }
}

// ---------------- softmax over 512-wide rows (wave per row) -------------------
__global__ __launch_bounds__(256) void softmax_k(const float* __restrict__ S,
                                                 f16* __restrict__ P) {
    int row = blockIdx.x * 4 + (threadIdx.x >> 6);
    int lane = threadIdx.x & 63;
    const float* src = S + (size_t)row * 512 + lane * 8;
    float v[8];
    *(float4*)&v[0] = *(const float4*)src;
    *(float4*)&v[4] = *(const float4*)(src + 4);
    float m = v[0];
#pragma unroll
    for (int i = 1; i < 8; ++i) m = fmaxf(m, v[i]);
#pragma unroll
    for (int off = 1; off < 64; off <<= 1) m = fmaxf(m, __shfl_xor(m, off, 64));
    float s = 0.f, e[8];
#pragma unroll
    for (int i = 0; i < 8; ++i) { e[i] = __expf(v[i] - m); s += e[i]; }
#pragma unroll
    for (int off = 1; off < 64; off <<= 1) s += __shfl_xor(s, off, 64);
    float inv = 1.0f / s;
    f16x8 pk;
#pragma unroll
    for (int i = 0; i < 8; ++i) pk[i] = (f16)(e[i] * inv);
    *(f16x8*)(P + (size_t)row * 512 + lane * 8) = pk;
}

// ---------------- launch ------------------------------------------------------
extern "C" void kernel_launch(void* const* d_in, const int* in_sizes, int n_in,
                              void* d_out, int out_size, void* d_ws, size_t ws_size,
                              hipStream_t stream) {
    const float* x = (const float*)d_in[0];
    const float* wqkv = (const float*)d_in[1];
    const float* wout = (const float*)d_in[2];
    const float* bout = (const float*)d_in[3];
    float* out = (float*)d_out;
    char* ws = (char*)d_ws;
    const size_t MBs = 1u << 20;

    f16* xb  = (f16*)(ws + 0);            // 32MB
    f16* wqb = (f16*)(ws + 32 * MBs);     // 1.5MB
    f16* wob = (f16*)(ws + 34 * MBs);     // 0.5MB
    f16* Qb  = (f16*)(ws + 35 * MBs);     // 32MB
    f16* Kb  = (f16*)(ws + 67 * MBs);     // 32MB
    f16* Vb  = (f16*)(ws + 99 * MBs);     // 32MB
    float* Sb = (float*)(ws + 131 * MBs); // 64MB
    f16* Pb  = xb;                        // alias: xb dead after qkv GEMM
    f16* yb  = Qb;                        // alias: Q dead after S GEMM

    prep_k<<<1024, 256, 0, stream>>>(x, wqkv, wout, xb, wqb, wob);
    g8_k<0><<<768, 512, 0, stream>>>(xb, wqb, Qb, Kb, Vb, nullptr);
    g8_k<1><<<256, 512, 0, stream>>>(Qb, Kb, Sb, nullptr, nullptr, nullptr);
    softmax_k<<<8192, 256, 0, stream>>>(Sb, Pb);
    g8_k<2><<<256, 512, 0, stream>>>(Pb, Vb, yb, nullptr, nullptr, nullptr);
    g8_k<3><<<256, 512, 0, stream>>>(yb, wob, out, nullptr, nullptr, bout);
}